// Round 9
// baseline (422.873 us; speedup 1.0000x reference)
//
#include <hip/hip_runtime.h>
#include <hip/hip_bf16.h>

#define N 8192
#define HID 64
#define JC 8    // J-chunks per I-tile: grid = 128*JC = 1024 blocks, 4/CU resident

typedef __attribute__((ext_vector_type(4))) float f32x4;
typedef __attribute__((ext_vector_type(8))) __bf16 bf16x8;

// async global->LDS, 16B per lane, dest = wave-uniform base + lane*16
__device__ __forceinline__ void gload_lds16(const void* g, float* l) {
  __builtin_amdgcn_global_load_lds(
      (const __attribute__((address_space(1))) void*)g,
      (__attribute__((address_space(3))) void*)l, 16, 0, 0);
}

// ---------------- Kernel A: projection + L2 normalize -> bf16 ----------------
// h = elu(x @ W1^T + b1); z = h @ W2^T + b2; zhat = z / max(||z||, 1e-12)
// One wave per row-iteration; lane j = output feature j. W1/W2 in LDS with
// stride-68 padding. Also zero-inits the 4*N stat array (replaces memset).
__global__ __launch_bounds__(256) void proj_kernel(
    const float* __restrict__ x1, const float* __restrict__ x2,
    const float* __restrict__ W1, const float* __restrict__ b1,
    const float* __restrict__ W2, const float* __restrict__ b2,
    __bf16* __restrict__ Z1h, __bf16* __restrict__ Z2h,
    float* __restrict__ stats)
{
  __shared__ __align__(16) float w1s[64*68];
  __shared__ __align__(16) float w2s[64*68];
  __shared__ __align__(16) float xs[4][64];
  __shared__ __align__(16) float hs[4][64];

  const int tid  = threadIdx.x;
  const int lane = tid & 63;
  const int w    = tid >> 6;

  int gtid = blockIdx.x * 256 + tid;
  if (gtid < 4*N) stats[gtid] = 0.f;

  for (int idx = tid; idx < 64*64; idx += 256) {
    int j = idx >> 6, k = idx & 63;
    w1s[j*68+k] = W1[idx];
    w2s[j*68+k] = W2[idx];
  }
  __syncthreads();

  const float bias1 = b1[lane];
  const float bias2 = b2[lane];

  const int wave_global = blockIdx.x * 4 + w;   // 0..4095 with grid=1024
  #pragma unroll 1
  for (int it = 0; it < 4; ++it) {
    int R = wave_global * 4 + it;               // 0..16383
    const float* src; __bf16* dst;
    if (R < N) { src = x1 + (size_t)R*HID;      dst = Z1h + (size_t)R*HID; }
    else       { src = x2 + (size_t)(R-N)*HID;  dst = Z2h + (size_t)(R-N)*HID; }

    float xv = src[lane];
    xs[w][lane] = xv;
    float acc = bias1;
    #pragma unroll
    for (int qq = 0; qq < 16; ++qq) {
      f32x4 xq = *(const f32x4*)&xs[w][qq*4];
      f32x4 wq = *(const f32x4*)&w1s[lane*68 + qq*4];
      acc += xq.x*wq.x + xq.y*wq.y + xq.z*wq.z + xq.w*wq.w;
    }
    float h = acc > 0.f ? acc : expm1f(acc);             // ELU (alpha=1)
    hs[w][lane] = h;
    float acc2 = bias2;
    #pragma unroll
    for (int qq = 0; qq < 16; ++qq) {
      f32x4 hq = *(const f32x4*)&hs[w][qq*4];
      f32x4 wq = *(const f32x4*)&w2s[lane*68 + qq*4];
      acc2 += hq.x*wq.x + hq.y*wq.y + hq.z*wq.z + hq.w*wq.w;
    }
    float z = acc2;
    float ss = z*z;
    #pragma unroll
    for (int m = 1; m < 64; m <<= 1) ss += __shfl_xor(ss, m);
    float inv = 1.0f / fmaxf(sqrtf(ss), 1e-12f);
    dst[lane] = (__bf16)(z * inv);
  }
}

// ---------------- Kernel B: exp-sim, counted-vmcnt pipelined ----------------
// Same verified data paths as R8 (swizzled Z-in-LDS staging, swapped-operand
// MFMA, pos f32x4 banks — all absmax 0); only the sync skeleton changes:
//   __syncthreads (vmcnt(0) drain each phase)  ->  raw s_barrier + vmcnt(4).
// Phase t: [STAGEZ(t+1)][LOADPOS(t+2)][STEP(t)][vmcnt(4)][s_barrier].
// Ledger (8 VMEM/phase, stage before pos): the 4 newest at the wait are
// pos(t+2) -> wait covers stage(t+1) (window = 1 compute phase, L2-fast) and
// leaves pos(t+2) in flight for a 2-PHASE window (~2x compute) -- matching its
// BW-serialized landing time. No wait in the loop drains a just-issued load
// (T4, m218). pos banks PA/PB/PC rotate period-3 (static names); Z dbuf
// parity 2 -> explicit 6-phase unrolled body x2 + 4-phase epilogue.
__global__ __launch_bounds__(256, 4) void sim_kernel(
    const __bf16* __restrict__ Z1h, const __bf16* __restrict__ Z2h,
    const float* __restrict__ pos,
    float* __restrict__ rowsum1, float* __restrict__ num1,
    float* __restrict__ rowsum2, float* __restrict__ num2)
{
  __shared__ __align__(16) float zs1[2][2048];   // 64 rows x 128B, double buf
  __shared__ __align__(16) float zs2[2][2048];   // 32 KB total

  const int tid  = threadIdx.x;
  const int lane = tid & 63;
  const int w    = tid >> 6;
  const int r16  = lane & 15;
  const int q    = lane >> 4;

  const int bi  = blockIdx.x / JC;    // 0..127 I-tile
  const int jc  = blockIdx.x % JC;
  const int i0  = bi*64 + w*16;

  // i-side fragments: row i0+r16, k = q*8 (lo) / +32 (hi)
  const __bf16* z1r = Z1h + (size_t)(i0 + r16)*HID + q*8;
  const __bf16* z2r = Z2h + (size_t)(i0 + r16)*HID + q*8;
  const bf16x8 a1lo = *(const bf16x8*)(z1r);
  const bf16x8 a1hi = *(const bf16x8*)(z1r + 32);
  const bf16x8 a2lo = *(const bf16x8*)(z2r);
  const bf16x8 a2hi = *(const bf16x8*)(z2r + 32);

  float s1 = 0.f, n1 = 0.f, s2 = 0.f, n2 = 0.f;

  const int jbeg = jc * (N/JC);               // 1024-col chunk, 16 x 64-col steps
  const float Cexp = 1.8033688011112042f;     // 1/(TAU*ln2), TAU=0.8
  const float* prow = pos + (size_t)(i0 + r16)*N + q*4;

  f32x4 PA0, PA1, PA2, PA3, PB0, PB1, PB2, PB3, PC0, PC1, PC2, PC3;

  // stage the 64-row j-tile of Z1+Z2 (16 KB/block, 4 insts/wave); source
  // slot (l&7)^r8 is the swizzle involution, LDS dest linear (verified R8)
#define STAGEZ(BUF, JJ) { \
    const int r8 = lane >> 3; \
    const int sl = (lane & 7) ^ r8; \
    gload_lds16(Z1h + (size_t)((JJ) + w*16     + r8)*HID + sl*8, &zs1[BUF][(w*16    )*32]); \
    gload_lds16(Z1h + (size_t)((JJ) + w*16 + 8 + r8)*HID + sl*8, &zs1[BUF][(w*16 + 8)*32]); \
    gload_lds16(Z2h + (size_t)((JJ) + w*16     + r8)*HID + sl*8, &zs2[BUF][(w*16    )*32]); \
    gload_lds16(Z2h + (size_t)((JJ) + w*16 + 8 + r8)*HID + sl*8, &zs2[BUF][(w*16 + 8)*32]); \
  }

#define LOADPOS(P, JJ) { \
    P##0 = *(const f32x4*)(prow + (JJ)); \
    P##1 = *(const f32x4*)(prow + (JJ) + 16); \
    P##2 = *(const f32x4*)(prow + (JJ) + 32); \
    P##3 = *(const f32x4*)(prow + (JJ) + 48); \
  }

  // one 16x16 j-subtile: swizzled LDS fragment reads + MFMA pair + exp + acc
#define COMPC(BUF, C, CC, PV) { \
    const int R  = (CC) + (C)*16 + r16; \
    const int sw = r16 & 7; \
    bf16x8 b2lo = *(const bf16x8*)&zs2[BUF][R*32 + ((q    ) ^ sw)*4]; \
    bf16x8 b2hi = *(const bf16x8*)&zs2[BUF][R*32 + ((q + 4) ^ sw)*4]; \
    bf16x8 b1lo = *(const bf16x8*)&zs1[BUF][R*32 + ((q    ) ^ sw)*4]; \
    bf16x8 b1hi = *(const bf16x8*)&zs1[BUF][R*32 + ((q + 4) ^ sw)*4]; \
    f32x4 zero4 = {0.f,0.f,0.f,0.f}; \
    f32x4 d1 = __builtin_amdgcn_mfma_f32_16x16x32_bf16(b2lo, a1lo, zero4, 0,0,0); \
    d1       = __builtin_amdgcn_mfma_f32_16x16x32_bf16(b2hi, a1hi, d1,    0,0,0); \
    f32x4 d2 = __builtin_amdgcn_mfma_f32_16x16x32_bf16(b1lo, a2lo, zero4, 0,0,0); \
    d2       = __builtin_amdgcn_mfma_f32_16x16x32_bf16(b1hi, a2hi, d2,    0,0,0); \
    _Pragma("unroll") \
    for (int r = 0; r < 4; ++r) { \
      float e1 = exp2f(d1[r] * Cexp); \
      float e2 = exp2f(d2[r] * Cexp); \
      s1 += e1; n1 += e1 * PV[r]; \
      s2 += e2; n2 += e2 * PV[r]; \
    } }

#define STEP(BUF, P) { COMPC(BUF,0,0,P##0) COMPC(BUF,1,0,P##1) COMPC(BUF,0,32,P##2) COMPC(BUF,1,32,P##3) }

  // full pipelined phase: stage(t+1), pos(t+2), compute(t), counted wait
#define PHASE(TB, TBN, PLOAD, PCONS, TT) { \
    STAGEZ(TBN, jbeg + ((TT)+1)*64) \
    LOADPOS(PLOAD, jbeg + ((TT)+2)*64) \
    STEP(TB, PCONS) \
    asm volatile("s_waitcnt vmcnt(4)" ::: "memory"); \
    __builtin_amdgcn_s_barrier(); \
  }

  // prologue: stage(0), pos(0), pos(1); land stage(0)+pos(0), pos(1) flies
  STAGEZ(0, jbeg)
  LOADPOS(PA, jbeg)
  LOADPOS(PB, jbeg + 64)
  asm volatile("s_waitcnt vmcnt(4)" ::: "memory");
  __builtin_amdgcn_s_barrier();

  // phases 0..11: period-6 pattern (Z parity 2 x pos banks 3), unrolled
  #pragma unroll 1
  for (int g = 0; g < 2; ++g) {
    const int t0 = g*6;
    PHASE(0, 1, PC, PA, t0+0)
    PHASE(1, 0, PA, PB, t0+1)
    PHASE(0, 1, PB, PC, t0+2)
    PHASE(1, 0, PC, PA, t0+3)
    PHASE(0, 1, PA, PB, t0+4)
    PHASE(1, 0, PB, PC, t0+5)
  }
  // phases 12..15 (epilogue: clamp loads at the chunk edge)
  PHASE(0, 1, PC, PA, 12)
  PHASE(1, 0, PA, PB, 13)
  // t=14: stage(15) only (no pos(16)); must land stage(15)+pos(15) -> drain
  STAGEZ(1, jbeg + 15*64)
  STEP(0, PC)
  asm volatile("s_waitcnt vmcnt(0)" ::: "memory");
  __builtin_amdgcn_s_barrier();
  // t=15: compute only
  STEP(1, PA)

#undef STAGEZ
#undef LOADPOS
#undef COMPC
#undef STEP
#undef PHASE

  // reduce j-partials across the 4 quads -> full sums per row i0+r16
  s1 += __shfl_xor(s1, 16); s1 += __shfl_xor(s1, 32);
  n1 += __shfl_xor(n1, 16); n1 += __shfl_xor(n1, 32);
  s2 += __shfl_xor(s2, 16); s2 += __shfl_xor(s2, 32);
  n2 += __shfl_xor(n2, 16); n2 += __shfl_xor(n2, 32);

  if (lane < 16) {
    int row = i0 + r16;
    atomicAdd(&rowsum1[row], s1);
    atomicAdd(&num1[row],    n1);
    atomicAdd(&rowsum2[row], s2);
    atomicAdd(&num2[row],    n2);
  }
}

// ---------------- Kernel C: final loss reduction ----------------
__global__ __launch_bounds__(1024) void loss_kernel(
    const float* __restrict__ rowsum1, const float* __restrict__ num1,
    const float* __restrict__ rowsum2, const float* __restrict__ num2,
    float* __restrict__ out)
{
  __shared__ float part[16];
  const int tid = threadIdx.x, lane = tid & 63, w = tid >> 6;
  float acc = 0.f;
  for (int i = tid; i < N; i += 1024) {
    float sc = -logf(num1[i]/(rowsum1[i]+1e-8f) + 1e-8f);
    float mp = -logf(num2[i]/(rowsum2[i]+1e-8f) + 1e-8f);
    acc += 0.5f*sc + 0.5f*mp;   // LAMBDA = 0.5
  }
  #pragma unroll
  for (int m = 1; m < 64; m <<= 1) acc += __shfl_xor(acc, m);
  if (lane == 0) part[w] = acc;
  __syncthreads();
  if (tid == 0) {
    float t = 0.f;
    #pragma unroll
    for (int k = 0; k < 16; ++k) t += part[k];
    out[0] = t * (1.0f/N);
  }
}

extern "C" void kernel_launch(void* const* d_in, const int* in_sizes, int n_in,
                              void* d_out, int out_size, void* d_ws, size_t ws_size,
                              hipStream_t stream) {
  const float* x1  = (const float*)d_in[0];
  const float* x2  = (const float*)d_in[1];
  const float* W1  = (const float*)d_in[2];
  const float* b1  = (const float*)d_in[3];
  const float* W2  = (const float*)d_in[4];
  const float* b2  = (const float*)d_in[5];
  const float* pos = (const float*)d_in[6];

  char* ws = (char*)d_ws;
  __bf16* Z1h = (__bf16*)ws;
  __bf16* Z2h = (__bf16*)(ws + (size_t)N*HID*sizeof(__bf16));
  size_t zbytes = (size_t)2*N*HID*sizeof(__bf16);   // 2 MB
  float* rowsum1 = (float*)(ws + zbytes);
  float* num1    = rowsum1 + N;
  float* rowsum2 = num1 + N;
  float* num2    = rowsum2 + N;

  proj_kernel<<<1024, 256, 0, stream>>>(x1, x2, W1, b1, W2, b2, Z1h, Z2h, rowsum1);
  sim_kernel<<<128*JC, 256, 0, stream>>>(Z1h, Z2h, pos, rowsum1, num1, rowsum2, num2);
  loss_kernel<<<1, 1024, 0, stream>>>(rowsum1, num1, rowsum2, num2, (float*)d_out);
}